// Round 3
// baseline (1047.571 us; speedup 1.0000x reference)
//
#include <hip/hip_runtime.h>
#include <hip/hip_bf16.h>
#include <stdint.h>
#include <stddef.h>

typedef __bf16 bf16;
typedef bf16  bf16x4 __attribute__((ext_vector_type(4)));
typedef bf16  bf16x8 __attribute__((ext_vector_type(8)));
typedef float f32x4  __attribute__((ext_vector_type(4)));

// ---------------------------------------------------------------------------
// async global->LDS, 16B per lane. LDS dest is wave-uniform base + lane*16.
// ---------------------------------------------------------------------------
__device__ __forceinline__ void async_copy16(bf16* lds, const bf16* g) {
    __builtin_amdgcn_global_load_lds(
        (const __attribute__((address_space(1))) void*)g,
        (__attribute__((address_space(3))) void*)lds,
        16, 0, 0);
}

// ---------------------------------------------------------------------------
// cast fp32 -> bf16, 4 elems/thread
// ---------------------------------------------------------------------------
__global__ __launch_bounds__(256) void cast_f32_to_bf16(
        const float* __restrict__ in, bf16* __restrict__ out, int n4) {
    int i = blockIdx.x * blockDim.x + threadIdx.x;
    if (i >= n4) return;
    const float4 v = *(const float4*)(in + (size_t)i * 4);
    bf16x4 o;
    o[0] = (bf16)v.x; o[1] = (bf16)v.y; o[2] = (bf16)v.z; o[3] = (bf16)v.w;
    *(bf16x4*)(out + (size_t)i * 4) = o;
}

// ---------------------------------------------------------------------------
// W_eff[n][k] = (q[n][k] - 7.5) * scale[n][k/64] + sum_r A[k][r]*Bm[r][n]
// LoRA operands in registers (A/B are L2-resident). See round-2 post-mortem.
// ---------------------------------------------------------------------------
__global__ __launch_bounds__(256) void dequant_lora(
        const int*   __restrict__ q,
        const float* __restrict__ scale,
        const float* __restrict__ A,
        const float* __restrict__ Bm,
        bf16* __restrict__ out,
        int N, int K) {
    const int tid = threadIdx.x;
    const int k0 = blockIdx.x * 64;
    const int n0 = blockIdx.y * 64;
    const int kk = k0 + (tid & 15) * 4;   // 4 consecutive k per thread
    const int nb = n0 + (tid >> 4) * 4;   // 4 consecutive n per thread

    f32x4 Ar[4][4];
    #pragma unroll
    for (int i = 0; i < 4; ++i)
        #pragma unroll
        for (int rq = 0; rq < 4; ++rq)
            Ar[i][rq] = *(const f32x4*)&A[(size_t)(kk + i) * 16 + rq * 4];
    f32x4 Br[16];
    #pragma unroll
    for (int r = 0; r < 16; ++r)
        Br[r] = *(const f32x4*)&Bm[(size_t)r * N + nb];

    const int scol = (unsigned)k0 >> 6;
    #pragma unroll
    for (int nn = 0; nn < 4; ++nn) {
        const int n = nb + nn;
        const int4 qv = *(const int4*)&q[(size_t)n * K + kk];
        const float s = scale[(size_t)n * (K >> 6) + scol];
        float l0 = 0.f, l1 = 0.f, l2 = 0.f, l3 = 0.f;
        #pragma unroll
        for (int r = 0; r < 16; ++r) {
            const float bv = Br[r][nn];
            l0 += Ar[0][r >> 2][r & 3] * bv;
            l1 += Ar[1][r >> 2][r & 3] * bv;
            l2 += Ar[2][r >> 2][r & 3] * bv;
            l3 += Ar[3][r >> 2][r & 3] * bv;
        }
        bf16x4 o;
        o[0] = (bf16)(((float)qv.x - 7.5f) * s + l0);
        o[1] = (bf16)(((float)qv.y - 7.5f) * s + l1);
        o[2] = (bf16)(((float)qv.z - 7.5f) * s + l2);
        o[3] = (bf16)(((float)qv.w - 7.5f) * s + l3);
        *(bf16x4*)&out[(size_t)n * K + kk] = o;
    }
}

// ---------------------------------------------------------------------------
// gemm_bt: C[m][n] = sum_k A[m][k] * B[n][k] + bias[n]   (optionally ReLU)
// m97 structure: 128x128 tile, BK=32, 4 waves, 4x4 16x16x32 MFMAs per wave.
// v3: coalesced epilogue — C-tile staged through LDS (32-row passes), written
// with 16B nontemporal stores. v2 scalar epilogue issued 64 scattered 2B/4B
// stores per thread and streamed 128/64 MB of C through L2 (evicting A/B).
// ---------------------------------------------------------------------------
template <bool RELU, typename OUT_T>
__global__ __launch_bounds__(256) void gemm_bt(
        const bf16* __restrict__ A, const bf16* __restrict__ B,
        const float* __restrict__ bias, OUT_T* __restrict__ C,
        int M, int N, int K) {
    __shared__ __attribute__((aligned(16))) bf16 As[128 * 32];
    __shared__ __attribute__((aligned(16))) bf16 Bs[128 * 32];
    // epilogue staging: stride padded for conflict-free quad writes,
    // rows 16B-aligned (144*2=288, 136*4=544, both %16==0)
    constexpr int CSTRIDE = (sizeof(OUT_T) == 2) ? 144 : 136;
    __shared__ __attribute__((aligned(16))) OUT_T Cstage[32][CSTRIDE];

    const int tid  = threadIdx.x;
    const int wave = tid >> 6;
    const int lane = tid & 63;

    // (kept from v2 — measured neutral) slab swizzle
    const int nbx = gridDim.x, nby = gridDim.y;
    const int GROUP = 16;
    const int linear = blockIdx.y * nbx + blockIdx.x;
    const int slab = linear / (GROUP * nby);
    const int rem  = linear % (GROUP * nby);
    const int bn = slab * GROUP + (rem % GROUP);
    const int bm = rem / GROUP;

    const int wm = (wave >> 1) << 6;   // 0 / 64
    const int wn = (wave & 1) << 6;    // 0 / 64

    const int srow = wave * 32 + (lane >> 2);
    const int scol = (lane & 3) * 8;
    const bf16* gA = A + (size_t)(bm * 128 + srow) * K + scol;
    const bf16* gB = B + (size_t)(bn * 128 + srow) * K + scol;
    bf16* lA0 = As + (wave * 2 + 0) * 512;
    bf16* lA1 = As + (wave * 2 + 1) * 512;
    bf16* lB0 = Bs + (wave * 2 + 0) * 512;
    bf16* lB1 = Bs + (wave * 2 + 1) * 512;

    const int fr = lane & 15;
    const int kq = lane >> 4;

    f32x4 acc[4][4];
    #pragma unroll
    for (int i = 0; i < 4; ++i)
        #pragma unroll
        for (int j = 0; j < 4; ++j) {
            f32x4 z = {0.f, 0.f, 0.f, 0.f};
            acc[i][j] = z;
        }

    for (int k0 = 0; k0 < K; k0 += 32) {
        __syncthreads();
        async_copy16(lA0, gA);
        async_copy16(lA1, gA + (size_t)16 * K);
        async_copy16(lB0, gB);
        async_copy16(lB1, gB + (size_t)16 * K);
        gA += 32; gB += 32;
        __syncthreads();

        bf16x8 fa[4], fb[4];
        #pragma unroll
        for (int i = 0; i < 4; ++i)
            fa[i] = *(const bf16x8*)(As + (wm + i * 16 + fr) * 32 + kq * 8);
        #pragma unroll
        for (int j = 0; j < 4; ++j)
            fb[j] = *(const bf16x8*)(Bs + (wn + j * 16 + fr) * 32 + kq * 8);

        #pragma unroll
        for (int i = 0; i < 4; ++i)
            #pragma unroll
            for (int j = 0; j < 4; ++j)
                acc[i][j] = __builtin_amdgcn_mfma_f32_16x16x32_bf16(
                    fa[i], fb[j], acc[i][j], 0, 0, 0);
    }

    // ---- epilogue: 4 passes of 32 rows through Cstage, 16B NT stores ----
    // C/D frag layout: row = wm + i*16 + quad*4 + r, col = wn + j*16 + (lane&15)
    const int quad  = lane >> 4;
    const int col16 = lane & 15;
    float bv[4];
    #pragma unroll
    for (int j = 0; j < 4; ++j)
        bv[j] = bias[bn * 128 + wn + j * 16 + col16];

    typedef OUT_T out_vec __attribute__((ext_vector_type(16 / sizeof(OUT_T))));
    constexpr int V   = 16 / (int)sizeof(OUT_T); // elems per 16B
    constexpr int TPR = 128 / V;                 // threads per row
    constexpr int RPH = 256 / TPR;               // rows per hop
    constexpr int HOPS = 32 / RPH;
    const int lrow = tid / TPR;
    const int lcol = (tid % TPR) * V;

    #pragma unroll
    for (int p = 0; p < 4; ++p) {
        __syncthreads();   // Cstage free (prev pass copied out)
        if (wm == (p >> 1) * 64) {
            #pragma unroll
            for (int i2 = 0; i2 < 2; ++i2) {
                const int i = (p & 1) * 2 + i2;
                #pragma unroll
                for (int j = 0; j < 4; ++j) {
                    #pragma unroll
                    for (int r = 0; r < 4; ++r) {
                        float v = acc[i][j][r] + bv[j];
                        if (RELU) v = v > 0.f ? v : 0.f;
                        Cstage[i2 * 16 + quad * 4 + r][wn + j * 16 + col16] =
                            (OUT_T)v;
                    }
                }
            }
        }
        __syncthreads();   // Cstage filled
        #pragma unroll
        for (int h = 0; h < HOPS; ++h) {
            const int rr = h * RPH + lrow;
            const out_vec val = *(const out_vec*)&Cstage[rr][lcol];
            OUT_T* dst = C + (size_t)(bm * 128 + p * 32 + rr) * N
                           + bn * 128 + lcol;
            __builtin_nontemporal_store(val, (out_vec*)dst);
        }
    }
}

// ---------------------------------------------------------------------------
extern "C" void kernel_launch(void* const* d_in, const int* in_sizes, int n_in,
                              void* d_out, int out_size, void* d_ws, size_t ws_size,
                              hipStream_t stream) {
    const float* x1           = (const float*)d_in[0];
    const int*   w_up_q       = (const int*)  d_in[1];
    const float* w_up_scale   = (const float*)d_in[2];
    const float* b_up         = (const float*)d_in[3];
    const float* w_up_lora_a  = (const float*)d_in[4];
    const float* w_up_lora_b  = (const float*)d_in[5];
    const int*   w_down_q     = (const int*)  d_in[6];
    const float* w_down_scale = (const float*)d_in[7];
    const float* b_down       = (const float*)d_in[8];
    const float* w_down_lora_a= (const float*)d_in[9];
    const float* w_down_lora_b= (const float*)d_in[10];
    float* out = (float*)d_out;

    const int M = 8192, D = 2048, H = 8192;

    char* ws = (char*)d_ws;
    bf16* x1b = (bf16*)ws;                                   // M*D   (32 MB)
    bf16* wup = (bf16*)(ws + (size_t)M * D * 2);             // H*D   (32 MB)
    bf16* x2  = (bf16*)(ws + (size_t)M * D * 2 + (size_t)H * D * 2); // M*H (128 MB)
    bf16* wdn = x1b;  // reuse region 0 after gemm1 consumed x1b

    {
        int n4 = (M * D) / 4;
        cast_f32_to_bf16<<<dim3((n4 + 255) / 256), dim3(256), 0, stream>>>(x1, x1b, n4);
    }
    dequant_lora<<<dim3(D / 64, H / 64), dim3(256), 0, stream>>>(
        w_up_q, w_up_scale, w_up_lora_a, w_up_lora_b, wup, H, D);
    gemm_bt<true, bf16><<<dim3(H / 128, M / 128), dim3(256), 0, stream>>>(
        x1b, wup, b_up, x2, M, H, D);
    dequant_lora<<<dim3(H / 64, D / 64), dim3(256), 0, stream>>>(
        w_down_q, w_down_scale, w_down_lora_a, w_down_lora_b, wdn, D, H);
    gemm_bt<false, float><<<dim3(D / 128, M / 128), dim3(256), 0, stream>>>(
        x2, wdn, b_down, out, M, D, H);
}

// Round 4
// 971.142 us; speedup vs baseline: 1.0787x; 1.0787x over previous
//
#include <hip/hip_runtime.h>
#include <hip/hip_bf16.h>
#include <stdint.h>
#include <stddef.h>

typedef __bf16 bf16;
typedef bf16  bf16x4 __attribute__((ext_vector_type(4)));
typedef bf16  bf16x8 __attribute__((ext_vector_type(8)));
typedef float f32x4  __attribute__((ext_vector_type(4)));

// ---------------------------------------------------------------------------
// async global->LDS, 16B per lane. LDS dest is wave-uniform base + lane*16.
// ---------------------------------------------------------------------------
__device__ __forceinline__ void async_copy16(bf16* lds, const bf16* g) {
    __builtin_amdgcn_global_load_lds(
        (const __attribute__((address_space(1))) void*)g,
        (__attribute__((address_space(3))) void*)lds,
        16, 0, 0);
}

// ---------------------------------------------------------------------------
// cast fp32 -> bf16, 4 elems/thread
// ---------------------------------------------------------------------------
__global__ __launch_bounds__(256) void cast_f32_to_bf16(
        const float* __restrict__ in, bf16* __restrict__ out, int n4) {
    int i = blockIdx.x * blockDim.x + threadIdx.x;
    if (i >= n4) return;
    const float4 v = *(const float4*)(in + (size_t)i * 4);
    bf16x4 o;
    o[0] = (bf16)v.x; o[1] = (bf16)v.y; o[2] = (bf16)v.z; o[3] = (bf16)v.w;
    *(bf16x4*)(out + (size_t)i * 4) = o;
}

// ---------------------------------------------------------------------------
// W_eff[n][k] = (q[n][k] - 7.5) * scale[n][k/64] + sum_r A[k][r]*Bm[r][n]
// LoRA operands in registers (A/B are L2-resident). See round-2 post-mortem.
// ---------------------------------------------------------------------------
__global__ __launch_bounds__(256) void dequant_lora(
        const int*   __restrict__ q,
        const float* __restrict__ scale,
        const float* __restrict__ A,
        const float* __restrict__ Bm,
        bf16* __restrict__ out,
        int N, int K) {
    const int tid = threadIdx.x;
    const int k0 = blockIdx.x * 64;
    const int n0 = blockIdx.y * 64;
    const int kk = k0 + (tid & 15) * 4;   // 4 consecutive k per thread
    const int nb = n0 + (tid >> 4) * 4;   // 4 consecutive n per thread

    f32x4 Ar[4][4];
    #pragma unroll
    for (int i = 0; i < 4; ++i)
        #pragma unroll
        for (int rq = 0; rq < 4; ++rq)
            Ar[i][rq] = *(const f32x4*)&A[(size_t)(kk + i) * 16 + rq * 4];
    f32x4 Br[16];
    #pragma unroll
    for (int r = 0; r < 16; ++r)
        Br[r] = *(const f32x4*)&Bm[(size_t)r * N + nb];

    const int scol = (unsigned)k0 >> 6;
    #pragma unroll
    for (int nn = 0; nn < 4; ++nn) {
        const int n = nb + nn;
        const int4 qv = *(const int4*)&q[(size_t)n * K + kk];
        const float s = scale[(size_t)n * (K >> 6) + scol];
        float l0 = 0.f, l1 = 0.f, l2 = 0.f, l3 = 0.f;
        #pragma unroll
        for (int r = 0; r < 16; ++r) {
            const float bv = Br[r][nn];
            l0 += Ar[0][r >> 2][r & 3] * bv;
            l1 += Ar[1][r >> 2][r & 3] * bv;
            l2 += Ar[2][r >> 2][r & 3] * bv;
            l3 += Ar[3][r >> 2][r & 3] * bv;
        }
        bf16x4 o;
        o[0] = (bf16)(((float)qv.x - 7.5f) * s + l0);
        o[1] = (bf16)(((float)qv.y - 7.5f) * s + l1);
        o[2] = (bf16)(((float)qv.z - 7.5f) * s + l2);
        o[3] = (bf16)(((float)qv.w - 7.5f) * s + l3);
        *(bf16x4*)&out[(size_t)n * K + kk] = o;
    }
}

// ---------------------------------------------------------------------------
// gemm_bt: C[m][n] = sum_k A[m][k] * B[n][k] + bias[n]   (optionally ReLU)
// 128x128 tile, BK=32, 4 waves, 4x4 16x16x32 MFMAs per wave.
// v4: DOUBLE-BUFFERED LDS. v3's loop was issue->vmcnt(0)->consume: zero
// intra-block latency hiding (MfmaUtil stuck at 26%). Now the prefetch for
// tile k+1 is issued after the single per-iter barrier and drains at the
// NEXT barrier, one full iteration later. Also 1 barrier/iter instead of 2.
// Epilogue: v2 direct stores (v3's LDS-staged epilogue measured -25 us).
// ---------------------------------------------------------------------------
template <bool RELU, typename OUT_T>
__global__ __launch_bounds__(256) void gemm_bt(
        const bf16* __restrict__ A, const bf16* __restrict__ B,
        const float* __restrict__ bias, OUT_T* __restrict__ C,
        int M, int N, int K) {
    __shared__ __attribute__((aligned(16))) bf16 As[2][128 * 32];
    __shared__ __attribute__((aligned(16))) bf16 Bs[2][128 * 32];

    const int tid  = threadIdx.x;
    const int wave = tid >> 6;
    const int lane = tid & 63;

    // (kept from v2 — measured neutral, harmless) slab swizzle
    const int nbx = gridDim.x, nby = gridDim.y;
    const int GROUP = 16;
    const int linear = blockIdx.y * nbx + blockIdx.x;
    const int slab = linear / (GROUP * nby);
    const int rem  = linear % (GROUP * nby);
    const int bn = slab * GROUP + (rem % GROUP);
    const int bm = rem / GROUP;

    const int wm = (wave >> 1) << 6;   // 0 / 64
    const int wn = (wave & 1) << 6;    // 0 / 64

    // staging: wave w stages rows [32w, 32w+32); lane L -> row 32w+L/4,
    // col (L%4)*8, i.e. contiguous 16B per lane within each 16-row chunk.
    const int srow = wave * 32 + (lane >> 2);
    const int scol = (lane & 3) * 8;
    const bf16* gA = A + (size_t)(bm * 128 + srow) * K + scol;
    const bf16* gB = B + (size_t)(bn * 128 + srow) * K + scol;
    const int c0 = (wave * 2 + 0) * 512;   // LDS elem offset, chunk 0
    const int c1 = (wave * 2 + 1) * 512;   // LDS elem offset, chunk 1

    const int fr = lane & 15;
    const int kq = lane >> 4;

    f32x4 acc[4][4];
    #pragma unroll
    for (int i = 0; i < 4; ++i)
        #pragma unroll
        for (int j = 0; j < 4; ++j) {
            f32x4 z = {0.f, 0.f, 0.f, 0.f};
            acc[i][j] = z;
        }

    // prologue: stage tile 0 into buffer 0
    async_copy16(&As[0][c0], gA);
    async_copy16(&As[0][c1], gA + (size_t)16 * K);
    async_copy16(&Bs[0][c0], gB);
    async_copy16(&Bs[0][c1], gB + (size_t)16 * K);
    gA += 32; gB += 32;

    const int niter = K >> 5;
    for (int k = 0; k < niter; ++k) {
        const int p = k & 1;
        // barrier: (a) drains vmcnt -> buf[p] staged; (b) all waves done
        // reading buf[p^1] from the previous iteration.
        __syncthreads();
        if (k + 1 < niter) {
            async_copy16(&As[p ^ 1][c0], gA);
            async_copy16(&As[p ^ 1][c1], gA + (size_t)16 * K);
            async_copy16(&Bs[p ^ 1][c0], gB);
            async_copy16(&Bs[p ^ 1][c1], gB + (size_t)16 * K);
            gA += 32; gB += 32;
        }

        bf16x8 fa[4], fb[4];
        #pragma unroll
        for (int i = 0; i < 4; ++i)
            fa[i] = *(const bf16x8*)(&As[p][(wm + i * 16 + fr) * 32 + kq * 8]);
        #pragma unroll
        for (int j = 0; j < 4; ++j)
            fb[j] = *(const bf16x8*)(&Bs[p][(wn + j * 16 + fr) * 32 + kq * 8]);

        #pragma unroll
        for (int i = 0; i < 4; ++i)
            #pragma unroll
            for (int j = 0; j < 4; ++j)
                acc[i][j] = __builtin_amdgcn_mfma_f32_16x16x32_bf16(
                    fa[i], fb[j], acc[i][j], 0, 0, 0);
    }

    // epilogue (v2): C/D layout col = lane&15, row = (lane>>4)*4 + reg
    const int erow = wm + (lane >> 4) * 4;
    const int ecol = wn + (lane & 15);
    #pragma unroll
    for (int j = 0; j < 4; ++j) {
        const int col = bn * 128 + ecol + j * 16;
        const float bv = bias[col];
        #pragma unroll
        for (int i = 0; i < 4; ++i) {
            #pragma unroll
            for (int r = 0; r < 4; ++r) {
                const int row = bm * 128 + erow + i * 16 + r;
                float v = acc[i][j][r] + bv;
                if (RELU) v = v > 0.f ? v : 0.f;
                C[(size_t)row * N + col] = (OUT_T)v;
            }
        }
    }
}

// ---------------------------------------------------------------------------
extern "C" void kernel_launch(void* const* d_in, const int* in_sizes, int n_in,
                              void* d_out, int out_size, void* d_ws, size_t ws_size,
                              hipStream_t stream) {
    const float* x1           = (const float*)d_in[0];
    const int*   w_up_q       = (const int*)  d_in[1];
    const float* w_up_scale   = (const float*)d_in[2];
    const float* b_up         = (const float*)d_in[3];
    const float* w_up_lora_a  = (const float*)d_in[4];
    const float* w_up_lora_b  = (const float*)d_in[5];
    const int*   w_down_q     = (const int*)  d_in[6];
    const float* w_down_scale = (const float*)d_in[7];
    const float* b_down       = (const float*)d_in[8];
    const float* w_down_lora_a= (const float*)d_in[9];
    const float* w_down_lora_b= (const float*)d_in[10];
    float* out = (float*)d_out;

    const int M = 8192, D = 2048, H = 8192;

    char* ws = (char*)d_ws;
    bf16* x1b = (bf16*)ws;                                   // M*D   (32 MB)
    bf16* wup = (bf16*)(ws + (size_t)M * D * 2);             // H*D   (32 MB)
    bf16* x2  = (bf16*)(ws + (size_t)M * D * 2 + (size_t)H * D * 2); // M*H (128 MB)
    bf16* wdn = x1b;  // reuse region 0 after gemm1 consumed x1b

    {
        int n4 = (M * D) / 4;
        cast_f32_to_bf16<<<dim3((n4 + 255) / 256), dim3(256), 0, stream>>>(x1, x1b, n4);
    }
    dequant_lora<<<dim3(D / 64, H / 64), dim3(256), 0, stream>>>(
        w_up_q, w_up_scale, w_up_lora_a, w_up_lora_b, wup, H, D);
    gemm_bt<true, bf16><<<dim3(H / 128, M / 128), dim3(256), 0, stream>>>(
        x1b, wup, b_up, x2, M, H, D);
    dequant_lora<<<dim3(H / 64, D / 64), dim3(256), 0, stream>>>(
        w_down_q, w_down_scale, w_down_lora_a, w_down_lora_b, wdn, D, H);
    gemm_bt<false, float><<<dim3(D / 128, M / 128), dim3(256), 0, stream>>>(
        x2, wdn, b_down, out, M, D, H);
}